// Round 4
// baseline (205.333 us; speedup 1.0000x reference)
//
#include <hip/hip_runtime.h>

#define NN 384
#define HH 768
#define HP 772   // padded LDS row: 8 row bases spread across bank quads, 16B aligned
#define L2E 1.4426950408889634f
#define TWO_L2E 2.8853900817779268f
#define INV_SQRT_H 0.03608439182435161f
#define ATT_L2E (INV_SQRT_H * L2E)   // att -> log2 domain in one constant

__device__ __forceinline__ float exp2_hw(float x) { return __builtin_amdgcn_exp2f(x); }
__device__ __forceinline__ float rcp_hw(float x) { return __builtin_amdgcn_rcpf(x); }
__device__ __forceinline__ float atomic_ld(const float* p) {   // coherent (IC) load, dodges stale XCD-L2
    return __hip_atomic_load(p, __ATOMIC_RELAXED, __HIP_MEMORY_SCOPE_AGENT);
}

// ---------------- workspace layout (floats) ----------------
#define WS_E(ws)      ((ws))
#define WS_ET(ws)     ((ws) + NN * NN)
#define WS_ROWP(ws)   ((ws) + 2 * NN * NN)            // [48][384] partial row sums of E
#define WS_COLP(ws)   ((ws) + 2 * NN * NN + 48 * NN)  // [48][384] partial col sums of E
#define WS_HYPERT(ws) ((ws) + 2 * NN * NN + 96 * NN)  // [384] hyper_typ
#define WS_HYPOT(ws)  (WS_HYPERT(ws) + NN)            // [384] hypo_typ
#define WS_HP(ws)     (WS_HYPOT(ws) + NN)             // [768] hyper prototype (atomic acc)
#define WS_HQ(ws)     (WS_HP(ws) + HH)                // [768] hypo prototype (atomic acc)
#define WS_CNT(ws)    ((unsigned int*)(WS_HQ(ws) + HH))  // [2] barrier counters

// ---------------- K1: one 8x8 tile of E = exp(att) + tile-partial row/col sums ------------
// R2's proven core: lane-per-output, 4 waves split k 4-ways, 4 independent trans chains.
// tanh(z)=1-2/(e^{2z}+1), y pre-scaled by 2*log2e. No softmax max needed: |att| <= 27.72
// so exp2(att*L2E) is in [9e-13, 1.1e12] (fp32-safe). Block 0 zero-inits the prototype
// accumulators and the two barrier counters for K2 (stream-ordered; ws arrives poisoned).
__global__ __launch_bounds__(256) void k_att(const float* __restrict__ X,
                                             const float* __restrict__ Y,
                                             float* __restrict__ ws) {
    __shared__ float smem[16 * HP + 256];
    float* xs = smem;
    float* ys = smem + 8 * HP;
    float* part = smem + 16 * HP;
    float* E = WS_E(ws);
    float* ET = WS_ET(ws);
    float* rowP = WS_ROWP(ws);
    float* colP = WS_COLP(ws);

    const int tid = threadIdx.x;
    const int tt = blockIdx.x;
    const int it = tt / 48, jt = tt - it * 48;
    const int i0 = it * 8, j0 = jt * 8;

    if (tt == 0) {   // init for K2's atomics + barrier (visible at K1->K2 dispatch boundary)
        float* pz = WS_HP(ws);
#pragma unroll
        for (int q = 0; q < 6; q++) pz[tid + q * 256] = 0.f;
        if (tid == 0) { WS_CNT(ws)[0] = 0u; WS_CNT(ws)[1] = 0u; }
    }

    const float4* gx = (const float4*)(X + i0 * HH);
    const float4* gy = (const float4*)(Y + j0 * HH);
#pragma unroll
    for (int p = 0; p < 6; p++) {
        int e = tid + p * 256;
        int r = e / 192, c = e - r * 192;
        float4 vx = gx[e];
        float4 vy = gy[e];
        ((float4*)(xs + r * HP))[c] = vx;
        vy.x *= TWO_L2E; vy.y *= TWO_L2E; vy.z *= TWO_L2E; vy.w *= TWO_L2E;
        ((float4*)(ys + r * HP))[c] = vy;
    }
    __syncthreads();

    const int wv = tid >> 6, ln = tid & 63;
    const int i = ln >> 3, j = ln & 7;
    const float4* xr = (const float4*)(xs + i * HP) + wv * 48;
    const float4* yr = (const float4*)(ys + j * HP) + wv * 48;
    float a0 = 0.f, a1 = 0.f, a2 = 0.f, a3 = 0.f;
#pragma unroll 8
    for (int m = 0; m < 48; m++) {
        float4 a = xr[m];
        float4 b = yr[m];
        a0 += rcp_hw(exp2_hw(a.x * b.x) + 1.f);
        a1 += rcp_hw(exp2_hw(a.y * b.y) + 1.f);
        a2 += rcp_hw(exp2_hw(a.z * b.z) + 1.f);
        a3 += rcp_hw(exp2_hw(a.w * b.w) + 1.f);
    }
    part[wv * 64 + ln] = (a0 + a1) + (a2 + a3);
    __syncthreads();
    if (tid < 64) {
        float s = part[tid] + part[64 + tid] + part[128 + tid] + part[192 + tid];
        float ev = exp2_hw((768.f - 2.f * s) * ATT_L2E);   // E = exp(att)
        int ii = tid >> 3, jj = tid & 7;
        E[(i0 + ii) * NN + (j0 + jj)] = ev;
        ET[(j0 + jj) * NN + (i0 + ii)] = ev;
        float rs = ev;   // row partial (sum over jj within tile)
        rs += __shfl_xor(rs, 1, 64); rs += __shfl_xor(rs, 2, 64); rs += __shfl_xor(rs, 4, 64);
        if (jj == 0) rowP[jt * NN + i0 + ii] = rs;
        float cs = ev;   // col partial (sum over ii within tile)
        cs += __shfl_xor(cs, 8, 64); cs += __shfl_xor(cs, 16, 64); cs += __shfl_xor(cs, 32, 64);
        if (ii == 0) colP[it * NN + j0 + jj] = cs;
    }
}

// ---------------- K2: typ -> [spin barrier] -> w+proto -> [last block] -> classifier -------
// 768 blocks, 256 thr, ~6.3 KB LDS, low VGPR -> residency capacity ~2048 blocks, so all
// 768 are co-resident and the counter barrier cannot deadlock. Counter lives at the
// device coherence point (AGENT-scope atomics); values crossing the barrier are read
// with AGENT atomic loads to bypass non-coherent per-XCD L2.
__global__ __launch_bounds__(256) void k_rest(const float* __restrict__ X,
                                              const float* __restrict__ Y,
                                              const float* __restrict__ W,
                                              const float* __restrict__ bias,
                                              float* __restrict__ ws,
                                              float* __restrict__ out) {
    __shared__ float red[4];
    __shared__ float redc[3][4];
    __shared__ int lastFlag;
    __shared__ float hps[HH], hqs[HH];
    const int b = blockIdx.x, tid = threadIdx.x;
    const bool isCol = b < NN;        // blocks 0..383: hyper side (typ_j, w_hyper[j], hp)
    const int x = isCol ? b : b - NN;
    const float* E = WS_E(ws);
    const float* ET = WS_ET(ws);
    const float* P = isCol ? WS_ROWP(ws) : WS_COLP(ws);
    const float* M = isCol ? ET : E;
    unsigned int* cnt = WS_CNT(ws);

    // ---- phase A: full sum vector from partials (redundant, L2-hot) + one typ value ----
    float s1 = 0.f, s2 = 0.f;
#pragma unroll 8
    for (int k = 0; k < 48; k++) {
        s1 += P[k * NN + tid];
        if (tid < 128) s2 += P[k * NN + tid + 256];
    }
    float r1 = rcp_hw(s1);                         // rowRS[tid] (or colRS[tid])
    float r2 = (tid < 128) ? rcp_hw(s2) : 0.f;     // ...[tid+256]
    float acc = M[x * NN + tid] * r1;
    if (tid < 128) acc += M[x * NN + tid + 256] * r2;
#pragma unroll
    for (int o = 32; o; o >>= 1) acc += __shfl_xor(acc, o, 64);
    if ((tid & 63) == 0) red[tid >> 6] = acc;
    __syncthreads();
    if (tid == 0) {
        float S = (red[0] + red[1]) + (red[2] + red[3]);
        (isCol ? WS_HYPERT(ws) : WS_HYPOT(ws))[x] = S * (1.f / NN);
        __threadfence();   // release typ before arrival
        __hip_atomic_fetch_add(&cnt[0], 1u, __ATOMIC_ACQ_REL, __HIP_MEMORY_SCOPE_AGENT);
        while (__hip_atomic_load(&cnt[0], __ATOMIC_ACQUIRE, __HIP_MEMORY_SCOPE_AGENT) < 768u)
            __builtin_amdgcn_s_sleep(2);
    }
    __syncthreads();   // whole block released once counter hits 768

    // ---- phase B: w value for this row/col + rank-1 prototype update ----
    const float* Tv = isCol ? WS_HYPOT(ws) : WS_HYPERT(ws);
    float acc2 = M[x * NN + tid] * r1 * atomic_ld(Tv + tid);
    if (tid < 128) acc2 += M[x * NN + tid + 256] * r2 * atomic_ld(Tv + tid + 256);
#pragma unroll
    for (int o = 32; o; o >>= 1) acc2 += __shfl_xor(acc2, o, 64);
    if ((tid & 63) == 0) red[tid >> 6] = acc2;
    __syncthreads();
    const float wj = (red[0] + red[1]) + (red[2] + red[3]);
    const float* V = isCol ? Y : X;
    float* proto = isCol ? WS_HP(ws) : WS_HQ(ws);
    atomicAdd(proto + tid,       wj * V[x * HH + tid]);
    atomicAdd(proto + tid + 256, wj * V[x * HH + tid + 256]);
    atomicAdd(proto + tid + 512, wj * V[x * HH + tid + 512]);

    // ---- last-arriving block runs the classifier ----
    __threadfence();
    __syncthreads();
    if (tid == 0) {
        unsigned int old = __hip_atomic_fetch_add(&cnt[1], 1u, __ATOMIC_ACQ_REL,
                                                  __HIP_MEMORY_SCOPE_AGENT);
        lastFlag = (old == 767u);
    }
    __syncthreads();
    if (!lastFlag) return;

    // stage prototypes to LDS via coherent loads (1536 atomic loads total)
#pragma unroll
    for (int q = 0; q < 3; q++) {
        hps[tid + q * 256] = atomic_ld(WS_HP(ws) + tid + q * 256);
        hqs[tid + q * 256] = atomic_ld(WS_HQ(ws) + tid + q * 256);
    }
    __syncthreads();

    float a0 = 0.f, a1 = 0.f, a2 = 0.f;
    for (int d = tid; d < 4 * HH; d += 256) {
        int seg = d / HH, r = d - seg * HH;
        float hpv = hps[r], hqv = hqs[r];
        float f = (seg == 0) ? hpv : (seg == 1) ? hqv : (seg == 2) ? (hpv - hqv) : (hpv * hqv);
        a0 += W[d] * f;
        a1 += W[3072 + d] * f;
        a2 += W[6144 + d] * f;
    }
#pragma unroll
    for (int o = 32; o; o >>= 1) {
        a0 += __shfl_xor(a0, o, 64);
        a1 += __shfl_xor(a1, o, 64);
        a2 += __shfl_xor(a2, o, 64);
    }
    if ((tid & 63) == 0) {
        redc[0][tid >> 6] = a0;
        redc[1][tid >> 6] = a1;
        redc[2][tid >> 6] = a2;
    }
    __syncthreads();
    if (tid < 3)
        out[tid] = redc[tid][0] + redc[tid][1] + redc[tid][2] + redc[tid][3] + bias[tid];
}

extern "C" void kernel_launch(void* const* d_in, const int* in_sizes, int n_in,
                              void* d_out, int out_size, void* d_ws, size_t ws_size,
                              hipStream_t stream) {
    const float* X = (const float*)d_in[0];   // hypo_embeddings [384,768] fp32
    const float* Y = (const float*)d_in[1];   // hyper_embeddings [384,768] fp32
    const float* W = (const float*)d_in[2];   // W_cls [3,3072] fp32
    const float* B = (const float*)d_in[3];   // b_cls [3] fp32
    float* out = (float*)d_out;
    float* ws = (float*)d_ws;

    k_att<<<2304, 256, 0, stream>>>(X, Y, ws);
    k_rest<<<768, 256, 0, stream>>>(X, Y, W, B, ws, out);
}

// Round 5
// 118.144 us; speedup vs baseline: 1.7380x; 1.7380x over previous
//
#include <hip/hip_runtime.h>

#define NN 384
#define HH 768
#define RP 388   // padded LDS row (floats): 97 16B-quads/row (odd) -> 8-row read groups conflict-free
#define L2E 1.4426950408889634f
#define TWO_L2E 2.8853900817779268f
#define INV_SQRT_H 0.03608439182435161f
#define ATT_L2E (INV_SQRT_H * L2E)   // att -> log2 domain in one constant
#define NT 24                        // 384/16 tiles per side

__device__ __forceinline__ float exp2_hw(float x) { return __builtin_amdgcn_exp2f(x); }
__device__ __forceinline__ float rcp_hw(float x) { return __builtin_amdgcn_rcpf(x); }

// ---------------- workspace layout (floats) ----------------
#define WS_E(ws)      ((ws))
#define WS_ET(ws)     ((ws) + NN * NN)
#define WS_ROWP(ws)   ((ws) + 2 * NN * NN)                 // [24][384] partial row sums of E
#define WS_COLP(ws)   (WS_ROWP(ws) + NT * NN)              // [24][384] partial col sums of E
#define WS_ROWRS(ws)  (WS_COLP(ws) + NT * NN)              // [384] 1/rowSum
#define WS_COLRS(ws)  (WS_ROWRS(ws) + NN)
#define WS_HYPERT(ws) (WS_COLRS(ws) + NN)
#define WS_HYPOT(ws)  (WS_HYPERT(ws) + NN)
#define WS_HP(ws)     (WS_HYPOT(ws) + NN)                  // [768] hyper prototype (atomic acc)
#define WS_HQ(ws)     (WS_HP(ws) + HH)                     // [768] hypo prototype (atomic acc)

// ---------------- K1: 16x16 tile of E = exp(att) + tile-partial row/col sums ------------
// Register 2x2 tiling: each thread owns outputs (r,c),(r,c+8),(r+8,c),(r+8,c+8) of its
// block tile; per float4-k-step it issues 4 ds_read_b128 feeding 16 tanh (0.25 reads/tanh,
// half of the 1-output-per-lane scheme -> LDS issue ~8.6us, below the 11.5us trans floor).
// 4 waves k-split; k staged in two 384-chunks (49.7KB LDS -> 3 blocks/CU). tanh(z) =
// 1 - 2/(e^{2z}+1), y pre-scaled by 2*log2e; per-element rcp(exp2+1) is overflow-safe
// (inf -> rcp -> 0 is the correct tanh saturation). No softmax max needed: |att| <= 27.72.
__global__ __launch_bounds__(256) void k_att(const float* __restrict__ X,
                                             const float* __restrict__ Y,
                                             float* __restrict__ ws) {
    __shared__ float smem[32 * RP];   // 49,664 B staging; reused for the output reduction
    float* E = WS_E(ws);
    float* ET = WS_ET(ws);
    float* rowP = WS_ROWP(ws);
    float* colP = WS_COLP(ws);

    const int tid = threadIdx.x;
    const int bb = blockIdx.x;                 // 576 = 24*24
    const int bi = bb / NT, bj = bb - bi * NT;
    const int i0 = bi * 16, j0 = bj * 16;

    if (bb == 0) {   // zero hp/hq for K3's atomicAdd (stream-ordered; ws arrives poisoned)
        float* pz = WS_HP(ws);
#pragma unroll
        for (int q = 0; q < 6; q++) pz[tid + q * 256] = 0.f;
    }

    const int wv = tid >> 6, ln = tid & 63;
    const int r = ln >> 3, c = ln & 7;         // 8x8 lane grid
    float a00 = 0.f, a01 = 0.f, a10 = 0.f, a11 = 0.f;

#pragma unroll
    for (int ch = 0; ch < 2; ch++) {
        const int kbase = ch * 384;
        // stage 32 rows (16 X + 16 Y) x 384 cols; Y pre-scaled by 2*log2e
#pragma unroll
        for (int p = 0; p < 12; p++) {
            int e = tid + p * 256;             // 0..3071 float4 slots
            int row = e / 96, col = e - row * 96;
            float4 v;
            if (row < 16) {
                v = *(const float4*)(X + (i0 + row) * HH + kbase + col * 4);
            } else {
                v = *(const float4*)(Y + (j0 + row - 16) * HH + kbase + col * 4);
                v.x *= TWO_L2E; v.y *= TWO_L2E; v.z *= TWO_L2E; v.w *= TWO_L2E;
            }
            *(float4*)(smem + row * RP + col * 4) = v;
        }
        __syncthreads();

        const float4* xa = (const float4*)(smem + r * RP) + wv * 24;
        const float4* xb = (const float4*)(smem + (r + 8) * RP) + wv * 24;
        const float4* ya = (const float4*)(smem + (16 + c) * RP) + wv * 24;
        const float4* yb = (const float4*)(smem + (24 + c) * RP) + wv * 24;
#pragma unroll 6
        for (int m = 0; m < 24; m++) {
            float4 x0 = xa[m], x1 = xb[m], y0 = ya[m], y1 = yb[m];
            a00 += rcp_hw(exp2_hw(x0.x * y0.x) + 1.f);
            a00 += rcp_hw(exp2_hw(x0.y * y0.y) + 1.f);
            a00 += rcp_hw(exp2_hw(x0.z * y0.z) + 1.f);
            a00 += rcp_hw(exp2_hw(x0.w * y0.w) + 1.f);
            a01 += rcp_hw(exp2_hw(x0.x * y1.x) + 1.f);
            a01 += rcp_hw(exp2_hw(x0.y * y1.y) + 1.f);
            a01 += rcp_hw(exp2_hw(x0.z * y1.z) + 1.f);
            a01 += rcp_hw(exp2_hw(x0.w * y1.w) + 1.f);
            a10 += rcp_hw(exp2_hw(x1.x * y0.x) + 1.f);
            a10 += rcp_hw(exp2_hw(x1.y * y0.y) + 1.f);
            a10 += rcp_hw(exp2_hw(x1.z * y0.z) + 1.f);
            a10 += rcp_hw(exp2_hw(x1.w * y0.w) + 1.f);
            a11 += rcp_hw(exp2_hw(x1.x * y1.x) + 1.f);
            a11 += rcp_hw(exp2_hw(x1.y * y1.y) + 1.f);
            a11 += rcp_hw(exp2_hw(x1.z * y1.z) + 1.f);
            a11 += rcp_hw(exp2_hw(x1.w * y1.w) + 1.f);
        }
        __syncthreads();   // chunk 1 restages over chunk 0
    }

    // ---- reduce 4 wave-partials per output; outputs indexed rr*16+cc (rr,cc in 0..15) ----
    float* part = smem;   // [4][256]
    part[wv * 256 + r * 16 + c]            = a00;
    part[wv * 256 + r * 16 + c + 8]        = a01;
    part[wv * 256 + (r + 8) * 16 + c]      = a10;
    part[wv * 256 + (r + 8) * 16 + c + 8]  = a11;
    __syncthreads();

    float s = part[tid] + part[256 + tid] + part[512 + tid] + part[768 + tid];
    float ev = exp2_hw((768.f - 2.f * s) * ATT_L2E);   // E = exp(att)
    const int rr = tid >> 4, cc = tid & 15;
    E[(i0 + rr) * NN + (j0 + cc)] = ev;
    ET[(j0 + cc) * NN + (i0 + rr)] = ev;

    // row partial: 16 consecutive lanes share rr -> in-wave shuffle reduce over cc
    float rs = ev;
    rs += __shfl_xor(rs, 1, 64); rs += __shfl_xor(rs, 2, 64);
    rs += __shfl_xor(rs, 4, 64); rs += __shfl_xor(rs, 8, 64);
    if (cc == 0) rowP[bj * NN + i0 + rr] = rs;

    // col partial: rr varies with stride 16 across waves -> via LDS
    __syncthreads();      // done reading part
    part[tid] = ev;
    __syncthreads();
    if (tid < 16) {
        float cs = 0.f;
#pragma unroll
        for (int q = 0; q < 16; q++) cs += part[q * 16 + tid];
        colP[bi * NN + j0 + tid] = cs;
    }
}

// ---------------- K2: typicalness vectors; blocks 0..383 cols, 384..767 rows ----------------
// Fully coalesced: [24][384] partial arrays + one contiguous E/ET row. Blocks 0 and 384
// publish the reciprocal row/col sums for K3.
__global__ __launch_bounds__(256) void k_typ(float* __restrict__ ws) {
    __shared__ float red[4];
    const int b = blockIdx.x, tid = threadIdx.x;
    const float* E = WS_E(ws);
    const float* ET = WS_ET(ws);
    const bool isCol = b < NN;
    const int x = isCol ? b : b - NN;
    const float* P = isCol ? WS_ROWP(ws) : WS_COLP(ws);
    const float* M = isCol ? ET : E;

    float s1 = 0.f, s2 = 0.f;
#pragma unroll 8
    for (int k = 0; k < NT; k++) {
        s1 += P[k * NN + tid];
        if (tid < 128) s2 += P[k * NN + tid + 256];
    }
    float r1 = rcp_hw(s1);
    float acc = M[x * NN + tid] * r1;
    float r2 = 0.f;
    if (tid < 128) {
        r2 = rcp_hw(s2);
        acc += M[x * NN + tid + 256] * r2;
    }
    if (isCol ? (b == 0) : (b == NN)) {   // publish reciprocals once for K3
        float* RS = isCol ? WS_ROWRS(ws) : WS_COLRS(ws);
        RS[tid] = r1;
        if (tid < 128) RS[tid + 256] = r2;
    }
#pragma unroll
    for (int o = 32; o; o >>= 1) acc += __shfl_xor(acc, o, 64);
    if ((tid & 63) == 0) red[tid >> 6] = acc;
    __syncthreads();
    if (tid == 0) {
        float S = (red[0] + red[1]) + (red[2] + red[3]);
        (isCol ? WS_HYPERT(ws) : WS_HYPOT(ws))[x] = S * (1.f / NN);
    }
}

// ---------------- K3: w-vectors + prototypes, fused ----------------
// 96 blocks, 8 w-values each. Block computes w_j by block-reduction, then applies the
// rank-1 update proto[d] += w_j * V[j][d]; one atomicAdd per (thread, d-slot) into ws
// (48 contenders/address spread over 1536 lines, relaxed — cheap, unlike R4's hot-line RMW).
__global__ __launch_bounds__(256) void k_wp(const float* __restrict__ X,
                                            const float* __restrict__ Y,
                                            float* __restrict__ ws) {
    __shared__ float red[4];
    const int bb = blockIdx.x, tid = threadIdx.x;
    const bool hyperSide = bb < 48;               // w_hyper -> hp (uses ET, rowRS, hypo_typ, Y)
    const int jbase = (hyperSide ? bb : bb - 48) * 8;
    const float* M  = hyperSide ? WS_ET(ws) : WS_E(ws);
    const float* RS = hyperSide ? WS_ROWRS(ws) : WS_COLRS(ws);
    const float* T  = hyperSide ? WS_HYPOT(ws) : WS_HYPERT(ws);
    const float* V  = hyperSide ? Y : X;
    float* proto    = hyperSide ? WS_HP(ws) : WS_HQ(ws);

    float p0 = 0.f, p1 = 0.f, p2 = 0.f;
#pragma unroll
    for (int q = 0; q < 8; q++) {
        const int jj = jbase + q;
        float acc = M[jj * NN + tid] * RS[tid] * T[tid];
        if (tid < 128) acc += M[jj * NN + tid + 256] * RS[tid + 256] * T[tid + 256];
#pragma unroll
        for (int o = 32; o; o >>= 1) acc += __shfl_xor(acc, o, 64);
        if ((tid & 63) == 0) red[tid >> 6] = acc;
        __syncthreads();
        const float wj = (red[0] + red[1]) + (red[2] + red[3]);
        p0 = fmaf(wj, V[jj * HH + tid], p0);
        p1 = fmaf(wj, V[jj * HH + tid + 256], p1);
        p2 = fmaf(wj, V[jj * HH + tid + 512], p2);
        __syncthreads();   // red[] reused next q
    }
    atomicAdd(proto + tid, p0);
    atomicAdd(proto + tid + 256, p1);
    atomicAdd(proto + tid + 512, p2);
}

// ---------------- K4: feats + classifier (1 block, plain stores to out) ----------------
__global__ __launch_bounds__(256) void k_cls(const float* __restrict__ W,
                                             const float* __restrict__ bias,
                                             const float* __restrict__ ws,
                                             float* __restrict__ out) {
    __shared__ float red[3][4];
    const int t = threadIdx.x;
    const float* hp = WS_HP((float*)ws);
    const float* hq = WS_HQ((float*)ws);
    float acc0 = 0.f, acc1 = 0.f, acc2 = 0.f;
    for (int d = t; d < 4 * HH; d += 256) {
        int seg = d / HH, r = d - seg * HH;
        float f = (seg == 0) ? hp[r] : (seg == 1) ? hq[r] : (seg == 2) ? (hp[r] - hq[r]) : (hp[r] * hq[r]);
        acc0 += W[d] * f;
        acc1 += W[3072 + d] * f;
        acc2 += W[6144 + d] * f;
    }
#pragma unroll
    for (int o = 32; o; o >>= 1) {
        acc0 += __shfl_xor(acc0, o, 64);
        acc1 += __shfl_xor(acc1, o, 64);
        acc2 += __shfl_xor(acc2, o, 64);
    }
    if ((t & 63) == 0) {
        red[0][t >> 6] = acc0;
        red[1][t >> 6] = acc1;
        red[2][t >> 6] = acc2;
    }
    __syncthreads();
    if (t < 3)
        out[t] = red[t][0] + red[t][1] + red[t][2] + red[t][3] + bias[t];
}

extern "C" void kernel_launch(void* const* d_in, const int* in_sizes, int n_in,
                              void* d_out, int out_size, void* d_ws, size_t ws_size,
                              hipStream_t stream) {
    const float* X = (const float*)d_in[0];   // hypo_embeddings [384,768] fp32
    const float* Y = (const float*)d_in[1];   // hyper_embeddings [384,768] fp32
    const float* W = (const float*)d_in[2];   // W_cls [3,3072] fp32
    const float* B = (const float*)d_in[3];   // b_cls [3] fp32
    float* out = (float*)d_out;
    float* ws = (float*)d_ws;

    k_att<<<576, 256, 0, stream>>>(X, Y, ws);
    k_typ<<<768, 256, 0, stream>>>(ws);
    k_wp<<<96, 256, 0, stream>>>(X, Y, ws);
    k_cls<<<1, 256, 0, stream>>>(W, B, ws, out);
}